// Round 6
// baseline (232.764 us; speedup 1.0000x reference)
//
#include <hip/hip_runtime.h>
#include <cstdint>

#define VDIM 10000
#define NROW 4096
#define DDIM 128
#define KSTEPS 313          // ceil(10000/32)
#define KSPLIT 8
#define KCHUNK 40           // ceil(313/8)
#define NCB 8               // 16-col blocks per kt tile

typedef __attribute__((ext_vector_type(8))) short bf16x8;
typedef __attribute__((ext_vector_type(4))) float f32x4;

__device__ __forceinline__ unsigned short f2bf(float f) {
    union { float f; unsigned u; } v; v.f = f;
    unsigned u = v.u;
    unsigned r = (u + 0x7FFFu + ((u >> 16) & 1u)) >> 16;  // RNE
    return (unsigned short)r;
}

// packed f32x4 pair -> bf16x8 via v_cvt_pk_bf16_f32 (RNE on gfx950)
__device__ __forceinline__ bf16x8 cvt8(f32x4 a, f32x4 b) {
    union { unsigned u[4]; bf16x8 v; } r;
    asm("v_cvt_pk_bf16_f32 %0, %1, %2" : "=v"(r.u[0]) : "v"(a[0]), "v"(a[1]));
    asm("v_cvt_pk_bf16_f32 %0, %1, %2" : "=v"(r.u[1]) : "v"(a[2]), "v"(a[3]));
    asm("v_cvt_pk_bf16_f32 %0, %1, %2" : "=v"(r.u[2]) : "v"(b[0]), "v"(b[1]));
    asm("v_cvt_pk_bf16_f32 %0, %1, %2" : "=v"(r.u[3]) : "v"(b[2]), "v"(b[3]));
    return r.v;
}

// ---------------------------------------------------------------------------
// Kernel 1: build fragment-major B: embF[e][kt][cb][lane][8] bf16
//   value = emb_e[col = cb*16 + (lane&15)][k = kt*32 + (lane>>4)*8 + j]
// One MFMA B-fragment load becomes ONE fully-coalesced dwordx4 per wave.
// Zero-padded for k >= VDIM (octet-granular; VDIM % 8 == 0).
// ---------------------------------------------------------------------------
__global__ __launch_bounds__(256) void build_embF(
    const float* __restrict__ ec, const float* __restrict__ er,
    unsigned short* __restrict__ embF)
{
    const int t = blockIdx.x * 256 + threadIdx.x;      // one thread -> 8 values
    const int perE = KSTEPS * NCB * 64;                // 160256
    if (t >= 2 * perE) return;
    const int e    = t / perE;
    const int rem  = t - e * perE;
    const int kt   = rem >> 9;                         // / (NCB*64)
    const int rem2 = rem & 511;
    const int cb   = rem2 >> 6;
    const int lane = rem2 & 63;
    const int col  = cb * 16 + (lane & 15);
    const int k0   = kt * 32 + (lane >> 4) * 8;

    unsigned short o[8];
    if (k0 + 8 <= VDIM) {
        const float* src = (e ? er : ec) + (size_t)col * VDIM + k0;
        #pragma unroll
        for (int j = 0; j < 8; ++j) o[j] = f2bf(src[j]);
    } else {
        #pragma unroll
        for (int j = 0; j < 8; ++j) o[j] = 0;
    }
    *reinterpret_cast<bf16x8*>(embF + (size_t)t * 8) =
        *reinterpret_cast<const bf16x8*>(o);
}

// ---------------------------------------------------------------------------
// Kernel 2: three GEMMs [4096,10000]x[10000,128] -> reps[3][4096][128] (f32)
// grid = (64 rb x 3 s x 8 kc) ; block 256 = 4 waves (2 wr x 2 wc).
// Wave tile: 32 rows x 64 cols, acc[2][4]. NO LDS, NO BARRIERS.
// B fragments read direct from fragment-major embF (coalesced, L2-hot).
// Depth-1 ping-pong prefetch of A (f32, 2 rowfrags) and B (4 colfrags).
// ---------------------------------------------------------------------------
__global__ __launch_bounds__(256, 4) void gemm_rep(
    const float* __restrict__ a0, const float* __restrict__ a1,
    const float* __restrict__ a2,
    const unsigned short* __restrict__ embF,
    float* __restrict__ reps)                 // [3][4096][128] f32 (zeroed)
{
    const int rb = blockIdx.x;                // 64 row-blocks of 64 rows
    const int s  = blockIdx.y;
    const int kc = blockIdx.z;
    const float* A = (s == 0) ? a0 : (s == 1 ? a1 : a2);
    const int e = (s == 0) ? 0 : 1;

    const int tid  = threadIdx.x;
    const int lane = tid & 63;
    const int w    = tid >> 6;
    const int wr   = w >> 1;                  // row-half of block tile
    const int wc   = w & 1;                   // col-half
    const int l15  = lane & 15;
    const int quad = lane >> 4;

    const int kt0 = kc * KCHUNK;
    const int kt1 = (kt0 + KCHUNK < KSTEPS) ? (kt0 + KCHUNK) : KSTEPS;

    const int rbase = rb * 64 + wr * 32;
    const float* apr0 = A + (size_t)(rbase + l15) * VDIM;
    const float* apr1 = A + (size_t)(rbase + 16 + l15) * VDIM;

    // B fragment base: embF[((e*KSTEPS+kt)*8 + wc*4+ct)*64 + lane]*8
    const unsigned short* bbase =
        embF + ((size_t)e * KSTEPS * NCB + wc * 4) * 512 + (size_t)lane * 8;

    f32x4 acc[2][4];
    #pragma unroll
    for (int rf = 0; rf < 2; ++rf)
        #pragma unroll
        for (int ct = 0; ct < 4; ++ct) acc[rf][ct] = (f32x4){0.f, 0.f, 0.f, 0.f};

    // named prefetch sets (no runtime indexing -> stays in VGPRs)
    f32x4 xa0, xa1, xa2, xa3;     bf16x8 xb0, xb1, xb2, xb3;   // set X
    f32x4 ya0, ya1, ya2, ya3;     bf16x8 yb0, yb1, yb2, yb3;   // set Y

#define CLAMPK(KT) (((KT) < KSTEPS - 1) ? (KT) : (KSTEPS - 1))

#define GLA(p0, p1, p2, p3, KT) do {                                   \
        int ko_ = (KT) * 32 + quad * 8;                                \
        ko_ = ko_ > (VDIM - 8) ? (VDIM - 8) : ko_;                     \
        p0 = *reinterpret_cast<const f32x4*>(apr0 + ko_);              \
        p1 = *reinterpret_cast<const f32x4*>(apr0 + ko_ + 4);          \
        p2 = *reinterpret_cast<const f32x4*>(apr1 + ko_);              \
        p3 = *reinterpret_cast<const f32x4*>(apr1 + ko_ + 4);          \
    } while (0)

#define GLB(q0, q1, q2, q3, KT) do {                                   \
        const unsigned short* b_ = bbase + (size_t)(KT) * 4096;        \
        q0 = *reinterpret_cast<const bf16x8*>(b_);                     \
        q1 = *reinterpret_cast<const bf16x8*>(b_ + 512);               \
        q2 = *reinterpret_cast<const bf16x8*>(b_ + 1024);              \
        q3 = *reinterpret_cast<const bf16x8*>(b_ + 1536);              \
    } while (0)

#define BODY(p0, p1, p2, p3, q0, q1, q2, q3) do {                      \
        bf16x8 af0_ = cvt8(p0, p1);                                    \
        bf16x8 af1_ = cvt8(p2, p3);                                    \
        acc[0][0] = __builtin_amdgcn_mfma_f32_16x16x32_bf16(af0_, q0, acc[0][0], 0, 0, 0); \
        acc[1][0] = __builtin_amdgcn_mfma_f32_16x16x32_bf16(af1_, q0, acc[1][0], 0, 0, 0); \
        acc[0][1] = __builtin_amdgcn_mfma_f32_16x16x32_bf16(af0_, q1, acc[0][1], 0, 0, 0); \
        acc[1][1] = __builtin_amdgcn_mfma_f32_16x16x32_bf16(af1_, q1, acc[1][1], 0, 0, 0); \
        acc[0][2] = __builtin_amdgcn_mfma_f32_16x16x32_bf16(af0_, q2, acc[0][2], 0, 0, 0); \
        acc[1][2] = __builtin_amdgcn_mfma_f32_16x16x32_bf16(af1_, q2, acc[1][2], 0, 0, 0); \
        acc[0][3] = __builtin_amdgcn_mfma_f32_16x16x32_bf16(af0_, q3, acc[0][3], 0, 0, 0); \
        acc[1][3] = __builtin_amdgcn_mfma_f32_16x16x32_bf16(af1_, q3, acc[1][3], 0, 0, 0); \
    } while (0)

    // prologue: set X <- kt0
    GLA(xa0, xa1, xa2, xa3, kt0);
    GLB(xb0, xb1, xb2, xb3, kt0);

    int kt = kt0;
    while (true) {
        // even phase: prefetch Y(t+1), consume X(t)
        GLA(ya0, ya1, ya2, ya3, CLAMPK(kt + 1));
        GLB(yb0, yb1, yb2, yb3, CLAMPK(kt + 1));
        BODY(xa0, xa1, xa2, xa3, xb0, xb1, xb2, xb3);
        if (++kt >= kt1) break;
        // odd phase: prefetch X(t+1), consume Y(t)
        GLA(xa0, xa1, xa2, xa3, CLAMPK(kt + 1));
        GLB(xb0, xb1, xb2, xb3, CLAMPK(kt + 1));
        BODY(ya0, ya1, ya2, ya3, yb0, yb1, yb2, yb3);
        if (++kt >= kt1) break;
    }

    // epilogue: C/D layout col = lane&15, row = quad*4 + reg
    float* rp = reps + (size_t)s * NROW * DDIM + (size_t)rbase * DDIM;
    #pragma unroll
    for (int rf = 0; rf < 2; ++rf)
        #pragma unroll
        for (int ct = 0; ct < 4; ++ct)
            #pragma unroll
            for (int r = 0; r < 4; ++r)
                atomicAdd(rp + (size_t)(rf * 16 + quad * 4 + r) * DDIM
                             + wc * 64 + ct * 16 + l15,
                          acc[rf][ct][r]);
#undef BODY
#undef GLB
#undef GLA
#undef CLAMPK
}

// ---------------------------------------------------------------------------
// Kernel 3: f_pos/f_neg row dots + hinge loss. wave-per-row, block = 4 waves
// ---------------------------------------------------------------------------
__global__ __launch_bounds__(256) void finalize(
    const float* __restrict__ reps, float* __restrict__ out)
{
    __shared__ float ls[4];
    const int wid  = threadIdx.x >> 6;
    const int lane = threadIdx.x & 63;
    const int row  = blockIdx.x * 4 + wid;

    const float* c = reps + (size_t)row * DDIM + 2 * lane;
    const float* r = c + (size_t)NROW * DDIM;
    const float* n = r + (size_t)NROW * DDIM;
    const float2 cv = *reinterpret_cast<const float2*>(c);
    const float2 rv = *reinterpret_cast<const float2*>(r);
    const float2 nv = *reinterpret_cast<const float2*>(n);

    float fp = cv.x * rv.x + cv.y * rv.y;
    float fn = cv.x * nv.x + cv.y * nv.y;
    #pragma unroll
    for (int off = 32; off > 0; off >>= 1) {
        fp += __shfl_down(fp, off);
        fn += __shfl_down(fn, off);
    }
    if (lane == 0) {
        out[row]        = fp;
        out[NROW + row] = fn;
        float t = fn - fp + 0.5f;
        ls[wid] = t > 0.f ? t : 0.f;
    }
    __syncthreads();
    if (threadIdx.x == 0)
        atomicAdd(out + 2 * NROW, ls[0] + ls[1] + ls[2] + ls[3]);
}

// ---------------------------------------------------------------------------
extern "C" void kernel_launch(void* const* d_in, const int* in_sizes, int n_in,
                              void* d_out, int out_size, void* d_ws, size_t ws_size,
                              hipStream_t stream)
{
    const float* cb  = (const float*)d_in[0];
    const float* rbb = (const float*)d_in[1];
    const float* nb  = (const float*)d_in[2];
    const float* ce  = (const float*)d_in[3];
    const float* re  = (const float*)d_in[4];
    float* out = (float*)d_out;

    unsigned short* embF = (unsigned short*)d_ws;
    const size_t embBytes = (size_t)2 * KSTEPS * NCB * 64 * 8 * sizeof(unsigned short); // 5.13 MB
    float* reps = (float*)((char*)d_ws + embBytes);
    const size_t repBytes = (size_t)3 * NROW * DDIM * sizeof(float);                    // 6.29 MB

    build_embF<<<dim3((2 * KSTEPS * NCB * 64 + 255) / 256), dim3(256), 0, stream>>>(ce, re, embF);
    hipMemsetAsync(reps, 0, repBytes, stream);
    hipMemsetAsync(out + 2 * NROW, 0, sizeof(float), stream);
    gemm_rep<<<dim3(NROW / 64, 3, KSPLIT), dim3(256), 0, stream>>>(cb, rbb, nb, embF, reps);
    finalize<<<dim3(NROW / 4), dim3(256), 0, stream>>>(reps, out);
}

// Round 7
// 196.004 us; speedup vs baseline: 1.1875x; 1.1875x over previous
//
#include <hip/hip_runtime.h>
#include <cstdint>

#define VDIM 10000
#define NROW 4096
#define DDIM 128
#define KSTEPS 313          // ceil(10000/32)
#define KSPLIT 8
#define KCHUNK 40           // ceil(313/8)
#define NCB 8               // 16-col blocks per kt tile

typedef __attribute__((ext_vector_type(8))) short bf16x8;
typedef __attribute__((ext_vector_type(4))) float f32x4;

__device__ __forceinline__ unsigned short f2bf(float f) {
    union { float f; unsigned u; } v; v.f = f;
    unsigned u = v.u;
    unsigned r = (u + 0x7FFFu + ((u >> 16) & 1u)) >> 16;  // RNE
    return (unsigned short)r;
}

// packed f32x4 pair -> bf16x8 via v_cvt_pk_bf16_f32 (RNE on gfx950)
__device__ __forceinline__ bf16x8 cvt8(f32x4 a, f32x4 b) {
    union { unsigned u[4]; bf16x8 v; } r;
    asm("v_cvt_pk_bf16_f32 %0, %1, %2" : "=v"(r.u[0]) : "v"(a[0]), "v"(a[1]));
    asm("v_cvt_pk_bf16_f32 %0, %1, %2" : "=v"(r.u[1]) : "v"(a[2]), "v"(a[3]));
    asm("v_cvt_pk_bf16_f32 %0, %1, %2" : "=v"(r.u[2]) : "v"(b[0]), "v"(b[1]));
    asm("v_cvt_pk_bf16_f32 %0, %1, %2" : "=v"(r.u[3]) : "v"(b[2]), "v"(b[3]));
    return r.v;
}

// ---------------------------------------------------------------------------
// Kernel 1: build fragment-major B: embF[e][kt][cb][lane][8] bf16
//   value = emb_e[col = cb*16 + (lane&15)][k = kt*32 + (lane>>4)*8 + j]
// Zero-padded for k >= VDIM (octet-granular; VDIM % 8 == 0).
// ---------------------------------------------------------------------------
__global__ __launch_bounds__(256) void build_embF(
    const float* __restrict__ ec, const float* __restrict__ er,
    unsigned short* __restrict__ embF)
{
    const int t = blockIdx.x * 256 + threadIdx.x;      // one thread -> 8 values
    const int perE = KSTEPS * NCB * 64;                // 160256
    if (t >= 2 * perE) return;
    const int e    = t / perE;
    const int rem  = t - e * perE;
    const int kt   = rem >> 9;                         // / (NCB*64)
    const int rem2 = rem & 511;
    const int cb   = rem2 >> 6;
    const int lane = rem2 & 63;
    const int col  = cb * 16 + (lane & 15);
    const int k0   = kt * 32 + (lane >> 4) * 8;

    unsigned short o[8];
    if (k0 + 8 <= VDIM) {
        const float* src = (e ? er : ec) + (size_t)col * VDIM + k0;
        #pragma unroll
        for (int j = 0; j < 8; ++j) o[j] = f2bf(src[j]);
    } else {
        #pragma unroll
        for (int j = 0; j < 8; ++j) o[j] = 0;
    }
    *reinterpret_cast<bf16x8*>(embF + (size_t)t * 8) =
        *reinterpret_cast<const bf16x8*>(o);
}

// ---------------------------------------------------------------------------
// Kernel 2: three GEMMs [4096,10000]x[10000,128] -> reps[3][4096][128] (f32)
// grid = (32 rb x 3 s x 8 kc) = 768 blocks = exactly 3 blocks/CU.
// block = 256 (4 waves); wave owns 32 UNIQUE rows x all 128 cols, acc[2][8].
// A path (the fix): per kt, lane loads 16 CONTIGUOUS floats of its row
// (coalesced), cvt_pk -> bf16, ds_write into wave-PRIVATE double-buffered
// LDS tile (72B-padded rows); MFMA A-frags via 2x ds_read_b128.
// No barriers anywhere (same-wave DS ops are in-order).
// B path: fragment-major embF direct-global, two 4-fragment phases per kt.
// ---------------------------------------------------------------------------
__global__ __launch_bounds__(256, 3) void gemm_rep(
    const float* __restrict__ a0, const float* __restrict__ a1,
    const float* __restrict__ a2,
    const unsigned short* __restrict__ embF,
    float* __restrict__ reps)                 // [3][4096][128] f32 (zeroed)
{
    __shared__ short aLds[4][2][32][36];      // wave-private, 72B rows, 18432 B

    const int rb = blockIdx.x;                // 32 row-blocks of 128 rows
    const int s  = blockIdx.y;
    const int kc = blockIdx.z;
    const float* A = (s == 0) ? a0 : (s == 1 ? a1 : a2);
    const int e = (s == 0) ? 0 : 1;

    const int tid  = threadIdx.x;
    const int lane = tid & 63;
    const int w    = tid >> 6;
    const int l15  = lane & 15;
    const int quad = lane >> 4;

    const int kt0 = kc * KCHUNK;
    const int kt1 = (kt0 + KCHUNK < KSTEPS) ? (kt0 + KCHUNK) : KSTEPS;

    const int rbase = rb * 128 + w * 32;
    // A staging: lane l covers row rbase + (l>>1), floats [kt*32+(l&1)*16, +16)
    const float* asrc = A + (size_t)(rbase + (lane >> 1)) * VDIM;
    const int fhalf = (lane & 1) * 16;        // float offset within kt-slab (=LDS short col)

    // B fragment base: embF[((e*KSTEPS+kt)*8 + ct)*64 + lane]*8
    const unsigned short* bbase =
        embF + (size_t)e * KSTEPS * NCB * 512 + (size_t)lane * 8;

    f32x4 acc[2][8];
    #pragma unroll
    for (int rf = 0; rf < 2; ++rf)
        #pragma unroll
        for (int ct = 0; ct < 8; ++ct) acc[rf][ct] = (f32x4){0.f, 0.f, 0.f, 0.f};

    f32x4 xa0, xa1, xa2, xa3;     // in-flight A slab (16 floats/lane)
    bf16x8 bA[4], bB[4];          // B fragment sets (cols 0-3 / 4-7)
    bf16x8 af0, af1;              // A fragments (rows l15 / l15+16)

#define CLAMPK(KT) (((KT) < KSTEPS - 1) ? (KT) : (KSTEPS - 1))

#define GLA(KT) do {                                                   \
        int f_ = (KT) * 32 + fhalf;                                    \
        f_ = f_ > (VDIM - 16) ? (VDIM - 16) : f_;                      \
        xa0 = *reinterpret_cast<const f32x4*>(asrc + f_);              \
        xa1 = *reinterpret_cast<const f32x4*>(asrc + f_ + 4);          \
        xa2 = *reinterpret_cast<const f32x4*>(asrc + f_ + 8);          \
        xa3 = *reinterpret_cast<const f32x4*>(asrc + f_ + 12);         \
    } while (0)

#define CVT_WR(P) do {                                                 \
        bf16x8 c0_ = cvt8(xa0, xa1);                                   \
        bf16x8 c1_ = cvt8(xa2, xa3);                                   \
        *reinterpret_cast<bf16x8*>(&aLds[w][P][lane >> 1][fhalf])     = c0_; \
        *reinterpret_cast<bf16x8*>(&aLds[w][P][lane >> 1][fhalf + 8]) = c1_; \
    } while (0)

#define GLB(REGS, CT0, KT) do {                                        \
        const unsigned short* b_ = bbase + ((size_t)(KT) * NCB + (CT0)) * 512; \
        REGS[0] = *reinterpret_cast<const bf16x8*>(b_);                \
        REGS[1] = *reinterpret_cast<const bf16x8*>(b_ + 512);          \
        REGS[2] = *reinterpret_cast<const bf16x8*>(b_ + 1024);         \
        REGS[3] = *reinterpret_cast<const bf16x8*>(b_ + 1536);         \
    } while (0)

#define FRAG(P) do {                                                   \
        af0 = *reinterpret_cast<const bf16x8*>(&aLds[w][P][l15][quad * 8]);      \
        af1 = *reinterpret_cast<const bf16x8*>(&aLds[w][P][l15 + 16][quad * 8]); \
    } while (0)

#define MFMA4(BS, C0) do {                                             \
        _Pragma("unroll")                                              \
        for (int j = 0; j < 4; ++j) {                                  \
            acc[0][(C0) + j] = __builtin_amdgcn_mfma_f32_16x16x32_bf16(af0, BS[j], acc[0][(C0) + j], 0, 0, 0); \
            acc[1][(C0) + j] = __builtin_amdgcn_mfma_f32_16x16x32_bf16(af1, BS[j], acc[1][(C0) + j], 0, 0, 0); \
        }                                                              \
    } while (0)

    // ---- prologue: buf0 <- A(kt0); prefetch B[0..3](kt0), A(kt0+1)
    GLA(kt0);
    GLB(bA, 0, kt0);
    CVT_WR(0);                 // waits A(kt0) once per block
    GLA(kt0 + 1);              // chunk length >= 33, always valid

    int kt = kt0, p = 0;
    while (true) {
        GLB(bB, 4, kt);                   // B[4..7](t)
        CVT_WR(p ^ 1);                    // publish A(t+1) (in-flight since t-1)
        if (kt + 2 < kt1) GLA(kt + 2);    // reissue A slab
        FRAG(p);                          // A(t) frags from LDS
        MFMA4(bA, 0);                     // cols 0..3
        GLB(bA, 0, CLAMPK(kt + 1));       // B[0..3](t+1)
        MFMA4(bB, 4);                     // cols 4..7
        if (++kt >= kt1) break;
        p ^= 1;
    }

    // epilogue: C/D layout col = lane&15, row = quad*4 + reg
    float* rp = reps + (size_t)s * NROW * DDIM + (size_t)rbase * DDIM;
    #pragma unroll
    for (int rf = 0; rf < 2; ++rf)
        #pragma unroll
        for (int ct = 0; ct < 8; ++ct)
            #pragma unroll
            for (int r = 0; r < 4; ++r)
                atomicAdd(rp + (size_t)(rf * 16 + quad * 4 + r) * DDIM + ct * 16 + l15,
                          acc[rf][ct][r]);
#undef MFMA4
#undef FRAG
#undef GLB
#undef CVT_WR
#undef GLA
#undef CLAMPK
}

// ---------------------------------------------------------------------------
// Kernel 3: f_pos/f_neg row dots + hinge loss. wave-per-row, block = 4 waves
// ---------------------------------------------------------------------------
__global__ __launch_bounds__(256) void finalize(
    const float* __restrict__ reps, float* __restrict__ out)
{
    __shared__ float ls[4];
    const int wid  = threadIdx.x >> 6;
    const int lane = threadIdx.x & 63;
    const int row  = blockIdx.x * 4 + wid;

    const float* c = reps + (size_t)row * DDIM + 2 * lane;
    const float* r = c + (size_t)NROW * DDIM;
    const float* n = r + (size_t)NROW * DDIM;
    const float2 cv = *reinterpret_cast<const float2*>(c);
    const float2 rv = *reinterpret_cast<const float2*>(r);
    const float2 nv = *reinterpret_cast<const float2*>(n);

    float fp = cv.x * rv.x + cv.y * rv.y;
    float fn = cv.x * nv.x + cv.y * nv.y;
    #pragma unroll
    for (int off = 32; off > 0; off >>= 1) {
        fp += __shfl_down(fp, off);
        fn += __shfl_down(fn, off);
    }
    if (lane == 0) {
        out[row]        = fp;
        out[NROW + row] = fn;
        float t = fn - fp + 0.5f;
        ls[wid] = t > 0.f ? t : 0.f;
    }
    __syncthreads();
    if (threadIdx.x == 0)
        atomicAdd(out + 2 * NROW, ls[0] + ls[1] + ls[2] + ls[3]);
}

// ---------------------------------------------------------------------------
extern "C" void kernel_launch(void* const* d_in, const int* in_sizes, int n_in,
                              void* d_out, int out_size, void* d_ws, size_t ws_size,
                              hipStream_t stream)
{
    const float* cb  = (const float*)d_in[0];
    const float* rbb = (const float*)d_in[1];
    const float* nb  = (const float*)d_in[2];
    const float* ce  = (const float*)d_in[3];
    const float* re  = (const float*)d_in[4];
    float* out = (float*)d_out;

    unsigned short* embF = (unsigned short*)d_ws;
    const size_t embBytes = (size_t)2 * KSTEPS * NCB * 64 * 8 * sizeof(unsigned short); // 5.13 MB
    float* reps = (float*)((char*)d_ws + embBytes);
    const size_t repBytes = (size_t)3 * NROW * DDIM * sizeof(float);                    // 6.29 MB

    build_embF<<<dim3((2 * KSTEPS * NCB * 64 + 255) / 256), dim3(256), 0, stream>>>(ce, re, embF);
    hipMemsetAsync(reps, 0, repBytes, stream);
    hipMemsetAsync(out + 2 * NROW, 0, sizeof(float), stream);
    gemm_rep<<<dim3(NROW / 128, 3, KSPLIT), dim3(256), 0, stream>>>(cb, rbb, nb, embF, reps);
    finalize<<<dim3(NROW / 4), dim3(256), 0, stream>>>(reps, out);
}

// Round 9
// 185.892 us; speedup vs baseline: 1.2521x; 1.0544x over previous
//
#include <hip/hip_runtime.h>
#include <cstdint>

#define VDIM 10000
#define NROW 4096
#define DDIM 128
#define KTPAD 320           // kt steps padded (320*32 = 10240)
#define KSPLIT 8
#define SLABS_PER_CHUNK 5   // 5 slabs * 8 kt * 32 k = 1280 k per chunk; 8*40=320 ✓
#define NCB 8               // 16-col blocks per kt tile

typedef __attribute__((ext_vector_type(8))) short bf16x8;
typedef __attribute__((ext_vector_type(4))) float f32x4;

__device__ __forceinline__ unsigned short f2bf(float f) {
    union { float f; unsigned u; } v; v.f = f;
    unsigned u = v.u;
    unsigned r = (u + 0x7FFFu + ((u >> 16) & 1u)) >> 16;  // RNE
    return (unsigned short)r;
}

// ---------------------------------------------------------------------------
// Kernel 1: build fragment-major B: embF[e][kt][cb][lane][8] bf16, kt < 320
//   value = emb_e[col = cb*16 + (lane&15)][k = kt*32 + (lane>>4)*8 + j]
// Zero for k+8 > VDIM (octet-granular; VDIM % 8 == 0) and all kt >= 313.
// ---------------------------------------------------------------------------
__global__ __launch_bounds__(256) void build_embF(
    const float* __restrict__ ec, const float* __restrict__ er,
    unsigned short* __restrict__ embF)
{
    const int t = blockIdx.x * 256 + threadIdx.x;      // one thread -> 8 values
    const int perE = KTPAD * NCB * 64;                 // 163840
    if (t >= 2 * perE) return;
    const int e    = t / perE;
    const int rem  = t - e * perE;
    const int kt   = rem >> 9;                         // / (NCB*64)
    const int rem2 = rem & 511;
    const int cb   = rem2 >> 6;
    const int lane = rem2 & 63;
    const int col  = cb * 16 + (lane & 15);
    const int k0   = kt * 32 + (lane >> 4) * 8;

    unsigned short o[8];
    if (k0 + 8 <= VDIM) {
        const float* src = (e ? er : ec) + (size_t)col * VDIM + k0;
        #pragma unroll
        for (int j = 0; j < 8; ++j) o[j] = f2bf(src[j]);
    } else {
        #pragma unroll
        for (int j = 0; j < 8; ++j) o[j] = 0;
    }
    *reinterpret_cast<bf16x8*>(embF + (size_t)t * 8) =
        *reinterpret_cast<const bf16x8*>(o);
}

// ---------------------------------------------------------------------------
// Kernel 2: three GEMMs [4096,10000]x[10000,128] -> reps[3][4096][128] f32.
// grid = (64 rb x 3 s x 8 kc) = 1536 blocks; block = 256 (4 waves).
// Wave owns 16 rows x 128 cols (acc[8]). K processed in 8-kt SLABS (256 f).
// A path: per slab, wave stages its 16 rows with 16 FULLY-COALESCED 1KB
// loads (lane i reads 16B at row_base + slab*1KB + i*16B), cvt_pk -> bf16,
// XOR-swizzled wave-PRIVATE LDS. No cross-wave sharing => NO BARRIERS.
// WAR/RAW within wave: DS ops in-order + compiler alias waits.
// B path: fragment-major embF, 1KB coalesced per fragment, L1/L2-hot.
// A(slab+1) issued before compute(slab) -> HBM latency hidden under MFMA.
// ---------------------------------------------------------------------------
__global__ __launch_bounds__(256, 2) void gemm_rep(
    const float* __restrict__ a0, const float* __restrict__ a1,
    const float* __restrict__ a2,
    const unsigned short* __restrict__ embF,
    float* __restrict__ reps)                 // [3][4096][128] f32 (zeroed)
{
    __shared__ short aLds[4][16][256];        // 32 KB, wave-private sections

    const int rb = blockIdx.x;                // 64 row-blocks of 64 rows
    const int s  = blockIdx.y;
    const int kc = blockIdx.z;
    const float* A = (s == 0) ? a0 : (s == 1 ? a1 : a2);
    const int e = (s == 0) ? 0 : 1;

    const int tid  = threadIdx.x;
    const int lane = tid & 63;
    const int w    = tid >> 6;
    const int l15  = lane & 15;
    const int quad = lane >> 4;

    const int slab0 = kc * SLABS_PER_CHUNK;   // slabs [slab0, slab0+5)
    const int rbase = rb * 64 + w * 16;       // wave's 16 rows
    const float* arow0 = A + (size_t)rbase * VDIM;

    // B fragment base: embF[((e*KTPAD + kt)*8 + ct)*512 + lane*8]
    const unsigned short* bbase =
        embF + (size_t)e * KTPAD * NCB * 512 + (size_t)lane * 8;

    f32x4 acc[8];
    #pragma unroll
    for (int ct = 0; ct < 8; ++ct) acc[ct] = (f32x4){0.f, 0.f, 0.f, 0.f};

    f32x4 sreg[16];                           // staged A slab (16 rows x 16B/lane)

#define GLA(SL) do {                                                   \
        int f_ = (SL) * 256 + lane * 4;                                \
        f_ = f_ > (VDIM - 4) ? (VDIM - 4) : f_;                        \
        _Pragma("unroll")                                              \
        for (int j = 0; j < 16; ++j)                                   \
            sreg[j] = *reinterpret_cast<const f32x4*>(                 \
                arow0 + (size_t)j * VDIM + f_);                        \
    } while (0)

#define CVTWRITE() do {                                                \
        _Pragma("unroll")                                              \
        for (int j = 0; j < 16; ++j) {                                 \
            union { unsigned u[2]; } p_;                               \
            asm("v_cvt_pk_bf16_f32 %0, %1, %2"                         \
                : "=v"(p_.u[0]) : "v"(sreg[j][0]), "v"(sreg[j][1]));   \
            asm("v_cvt_pk_bf16_f32 %0, %1, %2"                         \
                : "=v"(p_.u[1]) : "v"(sreg[j][2]), "v"(sreg[j][3]));   \
            int col_ = (lane * 4) ^ ((j & 7) << 3);                    \
            *reinterpret_cast<uint2*>(&aLds[w][j][col_]) =             \
                *reinterpret_cast<const uint2*>(p_.u);                 \
        }                                                              \
    } while (0)

    // ---- prologue
    GLA(slab0);

    #pragma unroll 1
    for (int si = 0; si < SLABS_PER_CHUNK; ++si) {
        CVTWRITE();                           // waits A(si) loads progressively
        if (si + 1 < SLABS_PER_CHUNK) GLA(slab0 + si + 1);  // in flight over compute
        const int skt = (slab0 + si) * 8;
        #pragma unroll
        for (int kts = 0; kts < 8; ++kts) {
            const unsigned short* bk = bbase + (size_t)(skt + kts) * (NCB * 512);
            bf16x8 af = *reinterpret_cast<const bf16x8*>(
                &aLds[w][l15][(kts * 32 + quad * 8) ^ ((l15 & 7) << 3)]);
            #pragma unroll
            for (int ct = 0; ct < 8; ++ct) {
                bf16x8 bq = *reinterpret_cast<const bf16x8*>(bk + ct * 512);
                acc[ct] = __builtin_amdgcn_mfma_f32_16x16x32_bf16(af, bq, acc[ct], 0, 0, 0);
            }
        }
    }

    // epilogue: C/D layout col = lane&15, row = quad*4 + reg
    float* rp = reps + (size_t)s * NROW * DDIM + (size_t)rbase * DDIM;
    #pragma unroll
    for (int ct = 0; ct < 8; ++ct)
        #pragma unroll
        for (int r = 0; r < 4; ++r)
            atomicAdd(rp + (size_t)(quad * 4 + r) * DDIM + ct * 16 + l15,
                      acc[ct][r]);
#undef CVTWRITE
#undef GLA
}

// ---------------------------------------------------------------------------
// Kernel 3: f_pos/f_neg row dots + hinge loss. wave-per-row, block = 4 waves
// ---------------------------------------------------------------------------
__global__ __launch_bounds__(256) void finalize(
    const float* __restrict__ reps, float* __restrict__ out)
{
    __shared__ float ls[4];
    const int wid  = threadIdx.x >> 6;
    const int lane = threadIdx.x & 63;
    const int row  = blockIdx.x * 4 + wid;

    const float* c = reps + (size_t)row * DDIM + 2 * lane;
    const float* r = c + (size_t)NROW * DDIM;
    const float* n = r + (size_t)NROW * DDIM;
    const float2 cv = *reinterpret_cast<const float2*>(c);
    const float2 rv = *reinterpret_cast<const float2*>(r);
    const float2 nv = *reinterpret_cast<const float2*>(n);

    float fp = cv.x * rv.x + cv.y * rv.y;
    float fn = cv.x * nv.x + cv.y * nv.y;
    #pragma unroll
    for (int off = 32; off > 0; off >>= 1) {
        fp += __shfl_down(fp, off);
        fn += __shfl_down(fn, off);
    }
    if (lane == 0) {
        out[row]        = fp;
        out[NROW + row] = fn;
        float t = fn - fp + 0.5f;
        ls[wid] = t > 0.f ? t : 0.f;
    }
    __syncthreads();
    if (threadIdx.x == 0)
        atomicAdd(out + 2 * NROW, ls[0] + ls[1] + ls[2] + ls[3]);
}

// ---------------------------------------------------------------------------
extern "C" void kernel_launch(void* const* d_in, const int* in_sizes, int n_in,
                              void* d_out, int out_size, void* d_ws, size_t ws_size,
                              hipStream_t stream)
{
    const float* cb  = (const float*)d_in[0];
    const float* rbb = (const float*)d_in[1];
    const float* nb  = (const float*)d_in[2];
    const float* ce  = (const float*)d_in[3];
    const float* re  = (const float*)d_in[4];
    float* out = (float*)d_out;

    unsigned short* embF = (unsigned short*)d_ws;
    const size_t embBytes = (size_t)2 * KTPAD * NCB * 512 * sizeof(unsigned short); // 5.24 MB
    float* reps = (float*)((char*)d_ws + embBytes);
    const size_t repBytes = (size_t)3 * NROW * DDIM * sizeof(float);                // 6.29 MB

    build_embF<<<dim3((2 * KTPAD * NCB * 64 + 255) / 256), dim3(256), 0, stream>>>(ce, re, embF);
    hipMemsetAsync(reps, 0, repBytes, stream);
    hipMemsetAsync(out + 2 * NROW, 0, sizeof(float), stream);
    gemm_rep<<<dim3(NROW / 64, 3, KSPLIT), dim3(256), 0, stream>>>(cb, rbb, nb, embF, reps);
    finalize<<<dim3(NROW / 4), dim3(256), 0, stream>>>(reps, out);
}

// Round 11
// 175.480 us; speedup vs baseline: 1.3264x; 1.0593x over previous
//
#include <hip/hip_runtime.h>
#include <cstdint>

#define VDIM 10000
#define NROW 4096
#define DDIM 128
#define KTPAD 320           // kt steps padded (320*32 = 10240)
#define KSPLIT 8
#define SLABS_PER_CHUNK 5   // 5 slabs * 8 kt * 32 k = 1280 k per chunk
#define NCB 8               // 16-col blocks per kt tile

typedef __attribute__((ext_vector_type(8))) short bf16x8;
typedef __attribute__((ext_vector_type(4))) float f32x4;

__device__ __forceinline__ unsigned short f2bf(float f) {
    union { float f; unsigned u; } v; v.f = f;
    unsigned u = v.u;
    unsigned r = (u + 0x7FFFu + ((u >> 16) & 1u)) >> 16;  // RNE
    return (unsigned short)r;
}

// ---------------------------------------------------------------------------
// Kernel 1: build fragment-major B: embF[e][kt][cb][lane][8] bf16, kt < 320
// ---------------------------------------------------------------------------
__global__ __launch_bounds__(256) void build_embF(
    const float* __restrict__ ec, const float* __restrict__ er,
    unsigned short* __restrict__ embF)
{
    const int t = blockIdx.x * 256 + threadIdx.x;
    const int perE = KTPAD * NCB * 64;                 // 163840
    if (t >= 2 * perE) return;
    const int e    = t / perE;
    const int rem  = t - e * perE;
    const int kt   = rem >> 9;
    const int rem2 = rem & 511;
    const int cb   = rem2 >> 6;
    const int lane = rem2 & 63;
    const int col  = cb * 16 + (lane & 15);
    const int k0   = kt * 32 + (lane >> 4) * 8;

    unsigned short o[8];
    if (k0 + 8 <= VDIM) {
        const float* src = (e ? er : ec) + (size_t)col * VDIM + k0;
        #pragma unroll
        for (int j = 0; j < 8; ++j) o[j] = f2bf(src[j]);
    } else {
        #pragma unroll
        for (int j = 0; j < 8; ++j) o[j] = 0;
    }
    *reinterpret_cast<bf16x8*>(embF + (size_t)t * 8) =
        *reinterpret_cast<const bf16x8*>(o);
}

// ---------------------------------------------------------------------------
// Shared GEMM core (R9 structure, verified): computes acc[8] for one
// (rb, s, kc) wave tile of 16 rows x 128 cols over 5 slabs of 8 kt.
// ---------------------------------------------------------------------------
#define GEMM_CORE_BODY                                                       \
    __shared__ short aLds[4][16][256];        /* 32 KB, wave-private */       \
    const int rb = blockIdx.x;                                                \
    const int s  = blockIdx.y;                                                \
    const int kc = blockIdx.z;                                                \
    const float* A = (s == 0) ? a0 : (s == 1 ? a1 : a2);                      \
    const int e = (s == 0) ? 0 : 1;                                           \
    const int tid  = threadIdx.x;                                             \
    const int lane = tid & 63;                                                \
    const int w    = tid >> 6;                                                \
    const int l15  = lane & 15;                                               \
    const int quad = lane >> 4;                                               \
    const int slab0 = kc * SLABS_PER_CHUNK;                                   \
    const int rbase = rb * 64 + w * 16;                                       \
    const float* arow0 = A + (size_t)rbase * VDIM;                            \
    const unsigned short* bbase =                                             \
        embF + (size_t)e * KTPAD * NCB * 512 + (size_t)lane * 8;              \
    f32x4 acc[8];                                                             \
    _Pragma("unroll")                                                         \
    for (int ct = 0; ct < 8; ++ct) acc[ct] = (f32x4){0.f, 0.f, 0.f, 0.f};     \
    f32x4 sreg[16];                                                           \
    GLA(slab0);                                                               \
    _Pragma("unroll 1")                                                       \
    for (int si = 0; si < SLABS_PER_CHUNK; ++si) {                            \
        CVTWRITE();                                                           \
        if (si + 1 < SLABS_PER_CHUNK) GLA(slab0 + si + 1);                    \
        const int skt = (slab0 + si) * 8;                                     \
        _Pragma("unroll")                                                     \
        for (int kts = 0; kts < 8; ++kts) {                                   \
            const unsigned short* bk = bbase + (size_t)(skt + kts) * (NCB * 512); \
            bf16x8 af = *reinterpret_cast<const bf16x8*>(                     \
                &aLds[w][l15][(kts * 32 + quad * 8) ^ ((l15 & 7) << 3)]);     \
            _Pragma("unroll")                                                 \
            for (int ct = 0; ct < 8; ++ct) {                                  \
                bf16x8 bq = *reinterpret_cast<const bf16x8*>(bk + ct * 512);  \
                acc[ct] = __builtin_amdgcn_mfma_f32_16x16x32_bf16(af, bq, acc[ct], 0, 0, 0); \
            }                                                                 \
        }                                                                     \
    }

#define GLA(SL) do {                                                   \
        int f_ = (SL) * 256 + lane * 4;                                \
        f_ = f_ > (VDIM - 4) ? (VDIM - 4) : f_;                        \
        _Pragma("unroll")                                              \
        for (int j = 0; j < 16; ++j)                                   \
            sreg[j] = *reinterpret_cast<const f32x4*>(                 \
                arow0 + (size_t)j * VDIM + f_);                        \
    } while (0)

#define CVTWRITE() do {                                                \
        _Pragma("unroll")                                              \
        for (int j = 0; j < 16; ++j) {                                 \
            union { unsigned u[2]; } p_;                               \
            asm("v_cvt_pk_bf16_f32 %0, %1, %2"                         \
                : "=v"(p_.u[0]) : "v"(sreg[j][0]), "v"(sreg[j][1]));   \
            asm("v_cvt_pk_bf16_f32 %0, %1, %2"                         \
                : "=v"(p_.u[1]) : "v"(sreg[j][2]), "v"(sreg[j][3]));   \
            int col_ = (lane * 4) ^ ((j & 7) << 3);                    \
            *reinterpret_cast<uint2*>(&aLds[w][j][col_]) =             \
                *reinterpret_cast<const uint2*>(p_.u);                 \
        }                                                              \
    } while (0)

// ---------------------------------------------------------------------------
// Kernel 2a (preferred): GEMM with PLAIN STORES to per-chunk partials
// reps8[kc][s][4096][128] f32 — ZERO atomics.
// ---------------------------------------------------------------------------
__global__ __launch_bounds__(256, 2) void gemm_rep_store(
    const float* __restrict__ a0, const float* __restrict__ a1,
    const float* __restrict__ a2,
    const unsigned short* __restrict__ embF,
    float* __restrict__ reps8)                // [8][3][4096][128] f32
{
    GEMM_CORE_BODY
    float* rp = reps8 + (((size_t)kc * 3 + s) * NROW + rbase) * DDIM;
    #pragma unroll
    for (int ct = 0; ct < 8; ++ct)
        #pragma unroll
        for (int r = 0; r < 4; ++r)
            rp[(size_t)(quad * 4 + r) * DDIM + ct * 16 + l15] = acc[ct][r];
}

// ---------------------------------------------------------------------------
// Kernel 2b (fallback, small ws): GEMM with atomicAdd into reps[3][4096][128]
// ---------------------------------------------------------------------------
__global__ __launch_bounds__(256, 2) void gemm_rep_atomic(
    const float* __restrict__ a0, const float* __restrict__ a1,
    const float* __restrict__ a2,
    const unsigned short* __restrict__ embF,
    float* __restrict__ reps)                 // [3][4096][128] f32 (zeroed)
{
    GEMM_CORE_BODY
    float* rp = reps + (size_t)s * NROW * DDIM + (size_t)rbase * DDIM;
    #pragma unroll
    for (int ct = 0; ct < 8; ++ct)
        #pragma unroll
        for (int r = 0; r < 4; ++r)
            atomicAdd(rp + (size_t)(quad * 4 + r) * DDIM + ct * 16 + l15,
                      acc[ct][r]);
}
#undef CVTWRITE
#undef GLA
#undef GEMM_CORE_BODY

// ---------------------------------------------------------------------------
// Kernel 3a: reduce 8 partial chunks + row dots + hinge loss. wave-per-row.
// ---------------------------------------------------------------------------
__global__ __launch_bounds__(256) void finalize8(
    const float* __restrict__ reps8, float* __restrict__ out)
{
    __shared__ float ls[4];
    const int wid  = threadIdx.x >> 6;
    const int lane = threadIdx.x & 63;
    const int row  = blockIdx.x * 4 + wid;

    float2 cs = {0.f, 0.f}, rs = {0.f, 0.f}, ns = {0.f, 0.f};
    #pragma unroll
    for (int kc = 0; kc < KSPLIT; ++kc) {
        const float* base = reps8 + ((size_t)kc * 3 * NROW + row) * DDIM + 2 * lane;
        const float2 cv = *reinterpret_cast<const float2*>(base);
        const float2 rv = *reinterpret_cast<const float2*>(base + (size_t)NROW * DDIM);
        const float2 nv = *reinterpret_cast<const float2*>(base + (size_t)2 * NROW * DDIM);
        cs.x += cv.x; cs.y += cv.y;
        rs.x += rv.x; rs.y += rv.y;
        ns.x += nv.x; ns.y += nv.y;
    }

    float fp = cs.x * rs.x + cs.y * rs.y;
    float fn = cs.x * ns.x + cs.y * ns.y;
    #pragma unroll
    for (int off = 32; off > 0; off >>= 1) {
        fp += __shfl_down(fp, off);
        fn += __shfl_down(fn, off);
    }
    if (lane == 0) {
        out[row]        = fp;
        out[NROW + row] = fn;
        float t = fn - fp + 0.5f;
        ls[wid] = t > 0.f ? t : 0.f;
    }
    __syncthreads();
    if (threadIdx.x == 0)
        atomicAdd(out + 2 * NROW, ls[0] + ls[1] + ls[2] + ls[3]);
}

// ---------------------------------------------------------------------------
// Kernel 3b: fallback finalize (reps already summed via atomics)
// ---------------------------------------------------------------------------
__global__ __launch_bounds__(256) void finalize1(
    const float* __restrict__ reps, float* __restrict__ out)
{
    __shared__ float ls[4];
    const int wid  = threadIdx.x >> 6;
    const int lane = threadIdx.x & 63;
    const int row  = blockIdx.x * 4 + wid;

    const float* c = reps + (size_t)row * DDIM + 2 * lane;
    const float2 cv = *reinterpret_cast<const float2*>(c);
    const float2 rv = *reinterpret_cast<const float2*>(c + (size_t)NROW * DDIM);
    const float2 nv = *reinterpret_cast<const float2*>(c + (size_t)2 * NROW * DDIM);

    float fp = cv.x * rv.x + cv.y * rv.y;
    float fn = cv.x * nv.x + cv.y * nv.y;
    #pragma unroll
    for (int off = 32; off > 0; off >>= 1) {
        fp += __shfl_down(fp, off);
        fn += __shfl_down(fn, off);
    }
    if (lane == 0) {
        out[row]        = fp;
        out[NROW + row] = fn;
        float t = fn - fp + 0.5f;
        ls[wid] = t > 0.f ? t : 0.f;
    }
    __syncthreads();
    if (threadIdx.x == 0)
        atomicAdd(out + 2 * NROW, ls[0] + ls[1] + ls[2] + ls[3]);
}

// ---------------------------------------------------------------------------
extern "C" void kernel_launch(void* const* d_in, const int* in_sizes, int n_in,
                              void* d_out, int out_size, void* d_ws, size_t ws_size,
                              hipStream_t stream)
{
    const float* cb  = (const float*)d_in[0];
    const float* rbb = (const float*)d_in[1];
    const float* nb  = (const float*)d_in[2];
    const float* ce  = (const float*)d_in[3];
    const float* re  = (const float*)d_in[4];
    float* out = (float*)d_out;

    unsigned short* embF = (unsigned short*)d_ws;
    const size_t embBytes   = (size_t)2 * KTPAD * NCB * 512 * sizeof(unsigned short); // 5.24 MB
    const size_t reps8Bytes = (size_t)KSPLIT * 3 * NROW * DDIM * sizeof(float);       // 50.3 MB
    const size_t repsBytes  = (size_t)3 * NROW * DDIM * sizeof(float);                // 6.29 MB

    build_embF<<<dim3((2 * KTPAD * NCB * 64 + 255) / 256), dim3(256), 0, stream>>>(ce, re, embF);
    hipMemsetAsync(out + 2 * NROW, 0, sizeof(float), stream);

    if (ws_size >= embBytes + reps8Bytes) {
        // preferred path: plain-store partials, zero atomics in GEMM
        float* reps8 = (float*)((char*)d_ws + embBytes);
        gemm_rep_store<<<dim3(NROW / 64, 3, KSPLIT), dim3(256), 0, stream>>>(
            cb, rbb, nb, embF, reps8);
        finalize8<<<dim3(NROW / 4), dim3(256), 0, stream>>>(reps8, out);
    } else {
        // fallback: atomic accumulation (R9 behavior)
        float* reps = (float*)((char*)d_ws + embBytes);
        hipMemsetAsync(reps, 0, repsBytes, stream);
        gemm_rep_atomic<<<dim3(NROW / 64, 3, KSPLIT), dim3(256), 0, stream>>>(
            cb, rbb, nb, embF, reps);
        finalize1<<<dim3(NROW / 4), dim3(256), 0, stream>>>(reps, out);
    }
}